// Round 18
// baseline (120.859 us; speedup 1.0000x reference)
//
#include <hip/hip_runtime.h>
#include <stdint.h>

#define DEVI __device__ __forceinline__

typedef __attribute__((ext_vector_type(8))) short short8;
typedef __attribute__((ext_vector_type(4))) float f32x4;
typedef __attribute__((ext_vector_type(4))) uint32_t u32x4;

DEVI unsigned short f2bf(float f) {
    union { float f; uint32_t u; } v; v.f = f;
    return (unsigned short)((v.u + 0x7FFFu + ((v.u >> 16) & 1u)) >> 16);
}

DEVI uint32_t cvtpk_bf16(float a, float b) {
    uint32_t r;
    asm("v_cvt_pk_bf16_f32 %0, %1, %2" : "=v"(r) : "v"(a), "v"(b));
    return r;   // lo16 = bf16(a), hi16 = bf16(b)
}

// D[32:63] <-> S[0:31]
DEVI void perm32(uint32_t &a, uint32_t &b) {
    asm("v_permlane32_swap_b32 %0, %1" : "+v"(a), "+v"(b));
}
// D[16:31] <-> S[0:15], D[48:63] <-> S[32:47]
DEVI void perm16(uint32_t &a, uint32_t &b) {
    asm("v_permlane16_swap_b32 %0, %1" : "+v"(a), "+v"(b));
}

DEVI void gload16(const void* g, void* l) {
    __builtin_amdgcn_global_load_lds(
        (const __attribute__((address_space(1))) unsigned int*)g,
        (__attribute__((address_space(3))) unsigned int*)l, 16, 0, 0);
}

// ---------------- fused prep: x f32->bf16, w_in^T, w_out^T (independent jobs) ----------------
__global__ __launch_bounds__(256) void k_prep(
    const float* __restrict__ x, ushort* __restrict__ xb,
    const float* __restrict__ w_in, ushort* __restrict__ w_inT,
    const float* __restrict__ w_out, ushort* __restrict__ w_outT)
{
    const int bid = blockIdx.x;
    if (bid < 2048) {
        const int n4 = 4096 * 1024 / 4;
        int i = bid * 256 + threadIdx.x;
        const int stride = 2048 * 256;
        for (; i < n4; i += stride) {
            float4 v = ((const float4*)x)[i];
            ushort4 o;
            o.x = f2bf(v.x); o.y = f2bf(v.y); o.z = f2bf(v.z); o.w = f2bf(v.w);
            ((ushort4*)xb)[i] = o;
        }
        return;
    }
    const float* in; ushort* out; int R, C, t;
    if (bid < 5120) { in = w_in;  out = w_inT;  R = 1024; C = 3072; t = bid - 2048; }
    else            { in = w_out; out = w_outT; R = 1024; C = 1024; t = bid - 5120; }
    const int tpr = C / 32;
    const int c0 = (t % tpr) * 32, r0 = (t / tpr) * 32;
    __shared__ float tl[32][33];
    int lr = threadIdx.x >> 5, lc = threadIdx.x & 31;
    #pragma unroll
    for (int i = 0; i < 4; i++)
        tl[lr + 8*i][lc] = in[(size_t)(r0 + lr + 8*i)*C + c0 + lc];
    __syncthreads();
    #pragma unroll
    for (int i = 0; i < 4; i++)
        out[(size_t)(c0 + lr + 8*i)*R + r0 + lc] = f2bf(tl[lc][lr + 8*i]);
}

// ---------------- GEMM (proven R10/R16 structure): C = A[M][K] * Bt[N][K]^T + bias --------------
// Tile: 128 x (NJ*32). NJ=4 -> 128x128 (4 waves x 64x64); NJ=2 -> 128x64 (4 waves x 64x32).
// MODE 0: split epilogue -> Q[B,H,S,64] (pre-scaled by log2e/8), K[B,H,S,64], V^T[B,H,64,S]
// MODE 1: fp32 out [M][N]
template<int MODE, int NJ>
__global__ __launch_bounds__(256, 2) void k_gemm(
    const ushort* __restrict__ A, const ushort* __restrict__ Bt,
    const float* __restrict__ bias,
    ushort* __restrict__ oQ, ushort* __restrict__ oK, ushort* __restrict__ oV,
    float* __restrict__ oF,
    int M, int N, int K, int S)
{
    __shared__ __align__(16) ushort As[128*64];
    __shared__ __align__(16) ushort Bs[NJ*32*64];
    const int tid = threadIdx.x;
    const int w = tid >> 6, l = tid & 63;

    int lin = blockIdx.y * gridDim.x + blockIdx.x;
    int nwg = gridDim.x * gridDim.y;
    int swz = (lin & 7) * (nwg >> 3) + (lin >> 3);
    const int m0 = (swz / gridDim.x) * 128, n0 = (swz % gridDim.x) * (NJ*32);

    const int wr = (w >> 1) * 64, wc = (w & 1) * (NJ*16);
    const int fr = l & 15, fg = l >> 4;
    const int lr8 = l >> 3;
    const int slot = (l & 7) ^ lr8;

    f32x4 acc[4][NJ] = {};

    const ushort* Abase = A + (size_t)(m0 + w*32 + lr8) * K + slot*8;
    const ushort* Bbase = Bt + (size_t)(n0 + w*(NJ*8) + lr8) * K + slot*8;

    for (int k0 = 0; k0 < K; k0 += 64) {
        __syncthreads();
        #pragma unroll
        for (int i = 0; i < 4; i++)
            gload16(Abase + (size_t)(8*i)*K + k0, &As[(w*32 + 8*i)*64]);
        #pragma unroll
        for (int i = 0; i < NJ; i++)
            gload16(Bbase + (size_t)(8*i)*K + k0, &Bs[(w*(NJ*8) + 8*i)*64]);
        __syncthreads();
        #pragma unroll
        for (int kk = 0; kk < 2; kk++) {
            short8 af[4], bfr[NJ];
            #pragma unroll
            for (int i = 0; i < 4; i++) {
                int ra = wr + i*16 + fr;
                af[i] = *(const short8*)((const char*)As + ra*128 + ((kk*64 + fg*16) ^ ((ra & 7) << 4)));
            }
            #pragma unroll
            for (int j = 0; j < NJ; j++) {
                int rb = wc + j*16 + fr;
                bfr[j] = *(const short8*)((const char*)Bs + rb*128 + ((kk*64 + fg*16) ^ ((rb & 7) << 4)));
            }
            #pragma unroll
            for (int i = 0; i < 4; i++)
                #pragma unroll
                for (int j = 0; j < NJ; j++)
                    acc[i][j] = __builtin_amdgcn_mfma_f32_16x16x32_bf16(af[i], bfr[j], acc[i][j], 0, 0, 0);
        }
    }

    if (MODE == 1) {
        #pragma unroll
        for (int j = 0; j < NJ; j++) {
            int n = n0 + wc + j*16 + fr;
            float bv = bias[n];
            #pragma unroll
            for (int i = 0; i < 4; i++) {
                int mrow = m0 + wr + i*16 + fg*4;
                #pragma unroll
                for (int r = 0; r < 4; r++)
                    oF[(size_t)(mrow + r)*N + n] = acc[i][j][r] + bv;
            }
        }
    } else {
        #pragma unroll
        for (int j = 0; j < NJ; j++) {
            int n = n0 + wc + j*16 + fr;
            int region = n >> 10;            // 0=Q 1=K 2=V
            int h = (n & 1023) >> 6;
            int d = n & 63;
            float bv = bias[n];
            float scl = (region == 0) ? 0.18033688011112042f : 1.0f;  // log2(e)/8 folded into Q
            #pragma unroll
            for (int i = 0; i < 4; i++) {
                int mrow = m0 + wr + i*16 + fg*4;
                int b = mrow >> 11;          // / 2048
                int s = mrow & 2047;
                if (region < 2) {
                    ushort* dst = (region == 0 ? oQ : oK) + ((size_t)(b*16 + h)*S)*64 + (size_t)d;
                    #pragma unroll
                    for (int r = 0; r < 4; r++)
                        dst[(size_t)(s + r)*64] = f2bf((acc[i][j][r] + bv) * scl);
                } else {
                    ushort* dst = oV + ((size_t)(b*16 + h)*64 + d)*S + s;
                    ushort4 pk;
                    pk.x = f2bf(acc[i][j][0] + bv);
                    pk.y = f2bf(acc[i][j][1] + bv);
                    pk.z = f2bf(acc[i][j][2] + bv);
                    pk.w = f2bf(acc[i][j][3] + bv);
                    *(ushort4*)dst = pk;
                }
            }
        }
    }
}

// ---------------- flash attention (causal): BQ=128/block (64 rows/wave), BKV=64 ----------------
// 512 blocks x 2 waves. Same 32 KB K/V double-buffered staging + barrier as R10, but each
// wave owns 64 q-rows (4 fragment tiles) -> stage/barrier overhead amortized 2x with LDS
// footprint unchanged. Body = two R10 sub-bodies (t-pairs, compile-time TP). Fully-future
// sub-tiles skipped per wave-uniform branch (no barriers inside body).
__global__ __launch_bounds__(128, 2) void k_attn(
    const ushort* __restrict__ Q,   // [B,H,S,64] (pre-scaled by log2e/8)
    const ushort* __restrict__ Kb,  // [B,H,S,64]
    const ushort* __restrict__ Vt,  // [B,H,64,S]
    ushort* __restrict__ O,         // [B*S][1024] bf16
    int S)
{
    __shared__ __align__(16) ushort Kt[2][64*64];
    __shared__ __align__(16) ushort Vs[2][64*64];

    const int tid = threadIdx.x, w = tid >> 6, l = tid & 63;
    const int bid = blockIdx.x;
    const int half = bid >> 8;           // heavy-first + complementary pairing
    const int r_ = bid & 255;
    const int h = r_ & 15, b = (r_ >> 4) & 1, p = r_ >> 5;   // p in [0,8)
    const int qt = half ? p : (15 - p);  // bids 0..255 -> qt 15..8 (heavy, dispatched first)
    const int bh = b * 16 + h;
    const int qw = qt * 128 + w * 64;    // wave's first q-row
    const int fr = l & 15, fg = l >> 4;

    // Q fragments (B-operand): qf[t][kk] = Q[qw + t*16 + fr][kk*32 + fg*8 + e], t=0..3
    short8 qf[4][2];
    {
        const ushort* qp = Q + ((size_t)bh*S + qw + fr)*64 + fg*8;
        #pragma unroll
        for (int t = 0; t < 4; t++) {
            qf[t][0] = *(const short8*)(qp + t*16*64);
            qf[t][1] = *(const short8*)(qp + t*16*64 + 32);
        }
    }

    float l_[4] = {0.f, 0.f, 0.f, 0.f};
    f32x4 o_[4][4] = {};   // o_[t][f][r] = O[q=qw+t*16+fr][dh=f*16+fg*4+r]

    const int lr8 = l >> 3;
    const int slot = (l & 7) ^ lr8;
    const ushort* Ksrc = Kb + (size_t)bh*S*64;
    const ushort* Vsrc = Vt + (size_t)bh*64*S;

    const int nt = 2*qt + 2;

    auto stage = [&](int buf, int j0) {
        #pragma unroll
        for (int i = 0; i < 4; i++) {
            int rb = w*32 + i*8;
            gload16(Ksrc + (size_t)(j0 + rb + lr8)*64 + slot*8, &Kt[buf][rb*64]);
            gload16(Vsrc + (size_t)(rb + lr8)*S + j0 + slot*8, &Vs[buf][rb*64]);
        }
    };

    stage(0, 0);
    __syncthreads();
    int cur = 0;

// one 32-row sub-body (rows qw + TP*32 .. +32) against KV tile at j0 — R10 math
#define BODY(TP) do {                                                                     \
    const int qbase = qw + (TP)*32;                                                       \
    if (j0 < qbase + 32) {              /* else tile fully future for these rows */       \
        const bool domask = (j0 + 64 > qbase);                                            \
        f32x4 sa[2][4] = {};                                                              \
        __builtin_amdgcn_s_setprio(1);                                                    \
        _Pragma("unroll")                                                                 \
        for (int kk = 0; kk < 2; kk++) {                                                  \
            short8 kf[4];                                                                 \
            _Pragma("unroll")                                                             \
            for (int f = 0; f < 4; f++) {                                                 \
                int row = f*16 + fr;                                                      \
                kf[f] = *(const short8*)((const char*)Kt[cur] + row*128 +                 \
                         ((kk*64 + fg*16) ^ ((row & 7) << 4)));                           \
            }                                                                             \
            _Pragma("unroll")                                                             \
            for (int t = 0; t < 2; t++)                                                   \
                _Pragma("unroll")                                                         \
                for (int f = 0; f < 4; f++)                                               \
                    sa[t][f] = __builtin_amdgcn_mfma_f32_16x16x32_bf16(                   \
                        kf[f], qf[(TP)*2 + t][kk], sa[t][f], 0, 0, 0);                    \
        }                                                                                 \
        __builtin_amdgcn_s_setprio(0);                                                    \
        if (domask) {                                                                     \
            _Pragma("unroll")                                                             \
            for (int t = 0; t < 2; t++) {                                                 \
                int qg = qbase + t*16 + fr;                                               \
                _Pragma("unroll")                                                         \
                for (int f = 0; f < 4; f++) {                                             \
                    int base = j0 + f*16 + fg*4 - qg;                                     \
                    _Pragma("unroll")                                                     \
                    for (int r = 0; r < 4; r++)                                           \
                        if (base + r > 0) sa[t][f][r] = -1e30f;                           \
                }                                                                         \
            }                                                                             \
        }                                                                                 \
        uint32_t cw[2][4][2];                                                             \
        _Pragma("unroll")                                                                 \
        for (int t = 0; t < 2; t++)                                                       \
            _Pragma("unroll")                                                             \
            for (int f = 0; f < 4; f++) {                                                 \
                float p0 = __builtin_amdgcn_exp2f(sa[t][f][0]);                           \
                float p1 = __builtin_amdgcn_exp2f(sa[t][f][1]);                           \
                float p2 = __builtin_amdgcn_exp2f(sa[t][f][2]);                           \
                float p3 = __builtin_amdgcn_exp2f(sa[t][f][3]);                           \
                l_[(TP)*2 + t] += (p0 + p1) + (p2 + p3);                                  \
                cw[t][f][0] = cvtpk_bf16(p0, p1);                                         \
                cw[t][f][1] = cvtpk_bf16(p2, p3);                                         \
            }                                                                             \
        __builtin_amdgcn_s_setprio(1);                                                    \
        _Pragma("unroll")                                                                 \
        for (int kk = 0; kk < 2; kk++) {                                                  \
            short8 pf[2];                                                                 \
            _Pragma("unroll")                                                             \
            for (int t = 0; t < 2; t++) {                                                 \
                uint32_t a0 = cw[t][2*kk][0], b0 = cw[t][2*kk + 1][0];                    \
                perm32(a0, b0); perm16(a0, b0);                                           \
                uint32_t a1 = cw[t][2*kk][1], b1 = cw[t][2*kk + 1][1];                    \
                perm32(a1, b1); perm16(a1, b1);                                           \
                u32x4 uw; uw[0] = a0; uw[1] = a1; uw[2] = b0; uw[3] = b1;                 \
                pf[t] = __builtin_bit_cast(short8, uw);                                   \
            }                                                                             \
            _Pragma("unroll")                                                             \
            for (int f = 0; f < 4; f++) {                                                 \
                int row = f*16 + fr;                                                      \
                short8 vf = *(const short8*)((const char*)Vs[cur] + row*128 +             \
                             ((kk*64 + fg*16) ^ ((row & 7) << 4)));                       \
                _Pragma("unroll")                                                         \
                for (int t = 0; t < 2; t++)                                               \
                    o_[(TP)*2 + t][f] = __builtin_amdgcn_mfma_f32_16x16x32_bf16(          \
                        vf, pf[t], o_[(TP)*2 + t][f], 0, 0, 0);                           \
            }                                                                             \
        }                                                                                 \
        __builtin_amdgcn_s_setprio(0);                                                    \
    }                                                                                     \
} while (0)

    for (int jt = 0; jt < nt; jt++) {
        const int j0 = jt * 64;
        if (jt + 1 < nt) stage(cur ^ 1, j0 + 64);
        BODY(0);
        BODY(1);
        __syncthreads();   // drains vmcnt(0) for prefetched stage + barrier
        cur ^= 1;
    }
#undef BODY

    // cross-lane l reduce (lanes fr, fr+16, fr+32, fr+48 share a q-row)
    #pragma unroll
    for (int t = 0; t < 4; t++) {
        l_[t] += __shfl_xor(l_[t], 16);
        l_[t] += __shfl_xor(l_[t], 32);
    }

    // epilogue: O[b*S + q][h*64 + dh], 4 consecutive dh per store
    #pragma unroll
    for (int t = 0; t < 4; t++) {
        float inv = 1.0f / l_[t];
        int qg = qw + t*16 + fr;
        #pragma unroll
        for (int f = 0; f < 4; f++) {
            ushort4 pk;
            pk.x = f2bf(o_[t][f][0] * inv);
            pk.y = f2bf(o_[t][f][1] * inv);
            pk.z = f2bf(o_[t][f][2] * inv);
            pk.w = f2bf(o_[t][f][3] * inv);
            *(ushort4*)&O[((size_t)(b*S + qg))*1024 + h*64 + f*16 + fg*4] = pk;
        }
    }
}

extern "C" void kernel_launch(void* const* d_in, const int* in_sizes, int n_in,
                              void* d_out, int out_size, void* d_ws, size_t ws_size,
                              hipStream_t stream)
{
    const float* x     = (const float*)d_in[0];
    const float* w_in  = (const float*)d_in[1];
    const float* b_in  = (const float*)d_in[2];
    const float* w_out = (const float*)d_in[3];
    const float* b_out = (const float*)d_in[4];
    float* out = (float*)d_out;

    const int B = 2, S = 2048, D = 1024, H = 16;
    const int M = B * S;  // 4096

    if (ws_size < (40u << 20)) return;
    char* ws = (char*)d_ws;
    ushort* xb     = (ushort*)(ws);              // 8MB: x bf16, later reused as attn_out
    ushort* w_inT  = (ushort*)(ws + (8u << 20)); // 6MB
    ushort* w_outT = (ushort*)(ws + (14u << 20));// 2MB
    ushort* qb     = (ushort*)(ws + (16u << 20));// 8MB
    ushort* kb     = (ushort*)(ws + (24u << 20));// 8MB
    ushort* vtb    = (ushort*)(ws + (32u << 20));// 8MB

    k_prep<<<6144, 256, 0, stream>>>(x, xb, w_in, w_inT, w_out, w_outT);
    k_gemm<0,4><<<dim3(3*D/128, M/128), 256, 0, stream>>>(xb, w_inT, b_in, qb, kb, vtb, nullptr, M, 3*D, D, S);
    k_attn<<<512, 128, 0, stream>>>(qb, kb, vtb, xb, S);
    k_gemm<1,2><<<dim3(D/64, M/128), 256, 0, stream>>>(xb, w_outT, b_out, nullptr, nullptr, nullptr, out, M, D, D, S);
}

// Round 19
// 102.378 us; speedup vs baseline: 1.1805x; 1.1805x over previous
//
#include <hip/hip_runtime.h>
#include <stdint.h>

#define DEVI __device__ __forceinline__

typedef __attribute__((ext_vector_type(8))) short short8;
typedef __attribute__((ext_vector_type(4))) float f32x4;
typedef __attribute__((ext_vector_type(4))) uint32_t u32x4;

DEVI unsigned short f2bf(float f) {
    union { float f; uint32_t u; } v; v.f = f;
    return (unsigned short)((v.u + 0x7FFFu + ((v.u >> 16) & 1u)) >> 16);
}

DEVI uint32_t cvtpk_bf16(float a, float b) {
    uint32_t r;
    asm("v_cvt_pk_bf16_f32 %0, %1, %2" : "=v"(r) : "v"(a), "v"(b));
    return r;   // lo16 = bf16(a), hi16 = bf16(b)
}

// D[32:63] <-> S[0:31]
DEVI void perm32(uint32_t &a, uint32_t &b) {
    asm("v_permlane32_swap_b32 %0, %1" : "+v"(a), "+v"(b));
}
// D[16:31] <-> S[0:15], D[48:63] <-> S[32:47]
DEVI void perm16(uint32_t &a, uint32_t &b) {
    asm("v_permlane16_swap_b32 %0, %1" : "+v"(a), "+v"(b));
}

DEVI void gload16(const void* g, void* l) {
    __builtin_amdgcn_global_load_lds(
        (const __attribute__((address_space(1))) unsigned int*)g,
        (__attribute__((address_space(3))) unsigned int*)l, 16, 0, 0);
}

// ---------------- fused prep: x f32->bf16, w_in^T, w_out^T (independent jobs) ----------------
// sections: [0,2048) cvt, [2048,5120) tcvt w_in (96x32 tiles), [5120,6144) tcvt w_out (32x32)
__global__ __launch_bounds__(256) void k_prep(
    const float* __restrict__ x, ushort* __restrict__ xb,
    const float* __restrict__ w_in, ushort* __restrict__ w_inT,
    const float* __restrict__ w_out, ushort* __restrict__ w_outT)
{
    const int bid = blockIdx.x;
    if (bid < 2048) {
        // x [4096][1024] f32 -> bf16, 4 elems/thread/iter
        const int n4 = 4096 * 1024 / 4;
        int i = bid * 256 + threadIdx.x;
        const int stride = 2048 * 256;
        for (; i < n4; i += stride) {
            float4 v = ((const float4*)x)[i];
            ushort4 o;
            o.x = f2bf(v.x); o.y = f2bf(v.y); o.z = f2bf(v.z); o.w = f2bf(v.w);
            ((ushort4*)xb)[i] = o;
        }
        return;
    }
    // transpose+convert sections
    const float* in; ushort* out; int R, C, t;
    if (bid < 5120) { in = w_in;  out = w_inT;  R = 1024; C = 3072; t = bid - 2048; }
    else            { in = w_out; out = w_outT; R = 1024; C = 1024; t = bid - 5120; }
    const int tpr = C / 32;                 // tiles per row of tiles
    const int c0 = (t % tpr) * 32, r0 = (t / tpr) * 32;
    __shared__ float tl[32][33];
    int lr = threadIdx.x >> 5, lc = threadIdx.x & 31;
    #pragma unroll
    for (int i = 0; i < 4; i++)
        tl[lr + 8*i][lc] = in[(size_t)(r0 + lr + 8*i)*C + c0 + lc];
    __syncthreads();
    #pragma unroll
    for (int i = 0; i < 4; i++)
        out[(size_t)(c0 + lr + 8*i)*R + r0 + lc] = f2bf(tl[lc][lr + 8*i]);
}

// ---------------- GEMM (proven R10 structure): C = A[M][K] * Bt[N][K]^T + bias ----------------
// Tile: 128 x (NJ*32). NJ=4 -> 128x128 (4 waves x 64x64); NJ=2 -> 128x64 (4 waves x 64x32).
// MODE 0: split epilogue -> Q[B,H,S,64] (pre-scaled by log2e/8), K[B,H,S,64], V^T[B,H,64,S]
// MODE 1: fp32 out [M][N]
template<int MODE, int NJ>
__global__ __launch_bounds__(256, 2) void k_gemm(
    const ushort* __restrict__ A, const ushort* __restrict__ Bt,
    const float* __restrict__ bias,
    ushort* __restrict__ oQ, ushort* __restrict__ oK, ushort* __restrict__ oV,
    float* __restrict__ oF,
    int M, int N, int K, int S)
{
    __shared__ __align__(16) ushort As[128*64];
    __shared__ __align__(16) ushort Bs[NJ*32*64];
    const int tid = threadIdx.x;
    const int w = tid >> 6, l = tid & 63;

    // XCD-aware swizzle (grid sizes are multiples of 8)
    int lin = blockIdx.y * gridDim.x + blockIdx.x;
    int nwg = gridDim.x * gridDim.y;
    int swz = (lin & 7) * (nwg >> 3) + (lin >> 3);
    const int m0 = (swz / gridDim.x) * 128, n0 = (swz % gridDim.x) * (NJ*32);

    const int wr = (w >> 1) * 64, wc = (w & 1) * (NJ*16);
    const int fr = l & 15, fg = l >> 4;
    const int lr8 = l >> 3;
    const int slot = (l & 7) ^ lr8;   // pre-swizzled global source slot (16B units)

    f32x4 acc[4][NJ] = {};

    const ushort* Abase = A + (size_t)(m0 + w*32 + lr8) * K + slot*8;
    const ushort* Bbase = Bt + (size_t)(n0 + w*(NJ*8) + lr8) * K + slot*8;

    for (int k0 = 0; k0 < K; k0 += 64) {
        __syncthreads();
        #pragma unroll
        for (int i = 0; i < 4; i++)
            gload16(Abase + (size_t)(8*i)*K + k0, &As[(w*32 + 8*i)*64]);
        #pragma unroll
        for (int i = 0; i < NJ; i++)
            gload16(Bbase + (size_t)(8*i)*K + k0, &Bs[(w*(NJ*8) + 8*i)*64]);
        __syncthreads();
        #pragma unroll
        for (int kk = 0; kk < 2; kk++) {
            short8 af[4], bfr[NJ];
            #pragma unroll
            for (int i = 0; i < 4; i++) {
                int ra = wr + i*16 + fr;
                af[i] = *(const short8*)((const char*)As + ra*128 + ((kk*64 + fg*16) ^ ((ra & 7) << 4)));
            }
            #pragma unroll
            for (int j = 0; j < NJ; j++) {
                int rb = wc + j*16 + fr;
                bfr[j] = *(const short8*)((const char*)Bs + rb*128 + ((kk*64 + fg*16) ^ ((rb & 7) << 4)));
            }
            #pragma unroll
            for (int i = 0; i < 4; i++)
                #pragma unroll
                for (int j = 0; j < NJ; j++)
                    acc[i][j] = __builtin_amdgcn_mfma_f32_16x16x32_bf16(af[i], bfr[j], acc[i][j], 0, 0, 0);
        }
    }

    if (MODE == 1) {
        #pragma unroll
        for (int j = 0; j < NJ; j++) {
            int n = n0 + wc + j*16 + fr;
            float bv = bias[n];
            #pragma unroll
            for (int i = 0; i < 4; i++) {
                int mrow = m0 + wr + i*16 + fg*4;
                #pragma unroll
                for (int r = 0; r < 4; r++)
                    oF[(size_t)(mrow + r)*N + n] = acc[i][j][r] + bv;
            }
        }
    } else {
        #pragma unroll
        for (int j = 0; j < NJ; j++) {
            int n = n0 + wc + j*16 + fr;
            int region = n >> 10;            // 0=Q 1=K 2=V
            int h = (n & 1023) >> 6;
            int d = n & 63;
            float bv = bias[n];
            float scl = (region == 0) ? 0.18033688011112042f : 1.0f;  // log2(e)/8 folded into Q
            #pragma unroll
            for (int i = 0; i < 4; i++) {
                int mrow = m0 + wr + i*16 + fg*4;
                int b = mrow >> 11;          // / 2048
                int s = mrow & 2047;
                if (region < 2) {
                    ushort* dst = (region == 0 ? oQ : oK) + ((size_t)(b*16 + h)*S)*64 + (size_t)d;
                    #pragma unroll
                    for (int r = 0; r < 4; r++)
                        dst[(size_t)(s + r)*64] = f2bf((acc[i][j][r] + bv) * scl);
                } else {
                    ushort* dst = oV + ((size_t)(b*16 + h)*64 + d)*S + s;
                    ushort4 pk;
                    pk.x = f2bf(acc[i][j][0] + bv);
                    pk.y = f2bf(acc[i][j][1] + bv);
                    pk.z = f2bf(acc[i][j][2] + bv);
                    pk.w = f2bf(acc[i][j][3] + bv);
                    *(ushort4*)dst = pk;
                }
            }
        }
    }
}

// ---------------- flash attention (causal), swapped-operand, no-max, P-in-register ----------------
// 2-wave blocks, BQ=64 (32 rows/wave), BKV=64, double-buffered K/V, permlane P routing.
// (R4/R10/R16-proven configuration: 42.5 us, best total; optimum of every axis probed
// around it: BQx2(R18), BKVx2(R14), V-from-global(R11), no-LDS(R7/R8), chunk-split(R6/R15),
// counted-vmcnt(R12), 8-wave residency(R9) all regressed or were neutral.)
__global__ __launch_bounds__(128, 2) void k_attn(
    const ushort* __restrict__ Q,   // [B,H,S,64] (pre-scaled by log2e/8)
    const ushort* __restrict__ Kb,  // [B,H,S,64]
    const ushort* __restrict__ Vt,  // [B,H,64,S]
    ushort* __restrict__ O,         // [B*S][1024] bf16
    int S)
{
    __shared__ __align__(16) ushort Kt[2][64*64];
    __shared__ __align__(16) ushort Vs[2][64*64];

    const int tid = threadIdx.x, w = tid >> 6, l = tid & 63;
    const int bid = blockIdx.x;
    const int half = bid >> 9;           // heavy-first + complementary pairing
    const int r_ = bid & 511;
    const int h = r_ & 15, b = (r_ >> 4) & 1, p = r_ >> 5;   // p in [0,16)
    const int qt = half ? p : (31 - p);  // bids 0..511 -> qt 16..31 (heavy, dispatched first)
    const int bh = b * 16 + h;
    const int qw = qt * 64 + w * 32;
    const int fr = l & 15, fg = l >> 4;

    // Q fragments (B-operand): Q[qw + t*16 + fr][kk*32 + fg*8 + e]
    short8 qf[2][2];
    {
        const ushort* qp = Q + ((size_t)bh*S + qw + fr)*64 + fg*8;
        qf[0][0] = *(const short8*)(qp);
        qf[0][1] = *(const short8*)(qp + 32);
        qf[1][0] = *(const short8*)(qp + 16*64);
        qf[1][1] = *(const short8*)(qp + 16*64 + 32);
    }

    float l_[2] = {0.f, 0.f};
    f32x4 o_[2][4] = {};   // o_[t][f][r] = O[q=qw+t*16+fr][dh=f*16+fg*4+r]

    const int lr8 = l >> 3;
    const int slot = (l & 7) ^ lr8;
    const ushort* Ksrc = Kb + (size_t)bh*S*64;
    const ushort* Vsrc = Vt + (size_t)bh*64*S;

    const int nt = qt + 1;

    auto stage = [&](int buf, int j0) {
        #pragma unroll
        for (int i = 0; i < 4; i++) {
            int rb = w*32 + i*8;
            gload16(Ksrc + (size_t)(j0 + rb + lr8)*64 + slot*8, &Kt[buf][rb*64]);
            gload16(Vsrc + (size_t)(rb + lr8)*S + j0 + slot*8, &Vs[buf][rb*64]);
        }
    };

    stage(0, 0);
    __syncthreads();
    int cur = 0;

    for (int jt = 0; jt < nt; jt++) {
        const int j0 = jt * 64;
        if (jt + 1 < nt) stage(cur ^ 1, j0 + 64);

        // QK^T: sa[t][f][r] = S[kv = j0+f*16+fg*4+r][q = qw+t*16+fr]
        f32x4 sa[2][4] = {};
        __builtin_amdgcn_s_setprio(1);
        #pragma unroll
        for (int kk = 0; kk < 2; kk++) {
            short8 kf[4];
            #pragma unroll
            for (int f = 0; f < 4; f++) {
                int row = f*16 + fr;
                kf[f] = *(const short8*)((const char*)Kt[cur] + row*128 + ((kk*64 + fg*16) ^ ((row & 7) << 4)));
            }
            #pragma unroll
            for (int t = 0; t < 2; t++)
                #pragma unroll
                for (int f = 0; f < 4; f++)
                    sa[t][f] = __builtin_amdgcn_mfma_f32_16x16x32_bf16(kf[f], qf[t][kk], sa[t][f], 0, 0, 0);
        }
        __builtin_amdgcn_s_setprio(0);

        // causal mask (diagonal tile only)
        if (jt == nt - 1) {
            #pragma unroll
            for (int t = 0; t < 2; t++) {
                int qg = qw + t*16 + fr;
                #pragma unroll
                for (int f = 0; f < 4; f++) {
                    int base = j0 + f*16 + fg*4 - qg;
                    #pragma unroll
                    for (int r = 0; r < 4; r++)
                        if (base + r > 0) sa[t][f][r] = -1e30f;
                }
            }
        }

        // no-max softmax: p = exp2(s); lane-partial l; pack to bf16 pairs in-register
        uint32_t cw[2][4][2];   // cw[t][f][rr] : bf16 pair (kv = f*16+fg*4+2rr, +1)
        #pragma unroll
        for (int t = 0; t < 2; t++)
            #pragma unroll
            for (int f = 0; f < 4; f++) {
                float p0 = __builtin_amdgcn_exp2f(sa[t][f][0]);
                float p1 = __builtin_amdgcn_exp2f(sa[t][f][1]);
                float p2 = __builtin_amdgcn_exp2f(sa[t][f][2]);
                float p3 = __builtin_amdgcn_exp2f(sa[t][f][3]);
                l_[t] += (p0 + p1) + (p2 + p3);
                cw[t][f][0] = cvtpk_bf16(p0, p1);
                cw[t][f][1] = cvtpk_bf16(p2, p3);
            }

        // PV: route P to B-fragments via permlane32/16 swaps (2 ops -> 2 words), then MFMA
        __builtin_amdgcn_s_setprio(1);
        #pragma unroll
        for (int kk = 0; kk < 2; kk++) {
            short8 pf[2];
            #pragma unroll
            for (int t = 0; t < 2; t++) {
                uint32_t a0 = cw[t][2*kk][0], b0 = cw[t][2*kk + 1][0];
                perm32(a0, b0); perm16(a0, b0);   // a0 = word0, b0 = word2
                uint32_t a1 = cw[t][2*kk][1], b1 = cw[t][2*kk + 1][1];
                perm32(a1, b1); perm16(a1, b1);   // a1 = word1, b1 = word3
                u32x4 uw; uw[0] = a0; uw[1] = a1; uw[2] = b0; uw[3] = b1;
                pf[t] = __builtin_bit_cast(short8, uw);
            }
            #pragma unroll
            for (int f = 0; f < 4; f++) {
                int row = f*16 + fr;
                short8 vf = *(const short8*)((const char*)Vs[cur] + row*128 + ((kk*64 + fg*16) ^ ((row & 7) << 4)));
                #pragma unroll
                for (int t = 0; t < 2; t++)
                    o_[t][f] = __builtin_amdgcn_mfma_f32_16x16x32_bf16(vf, pf[t], o_[t][f], 0, 0, 0);
            }
        }
        __builtin_amdgcn_s_setprio(0);

        __syncthreads();   // drains vmcnt(0) for prefetched stage + barrier
        cur ^= 1;
    }

    // cross-lane l reduce (lanes fr, fr+16, fr+32, fr+48 share a q-row)
    #pragma unroll
    for (int t = 0; t < 2; t++) {
        l_[t] += __shfl_xor(l_[t], 16);
        l_[t] += __shfl_xor(l_[t], 32);
    }

    // epilogue: O[b*S + q][h*64 + dh], 4 consecutive dh per store
    #pragma unroll
    for (int t = 0; t < 2; t++) {
        float inv = 1.0f / l_[t];
        int qg = qw + t*16 + fr;
        #pragma unroll
        for (int f = 0; f < 4; f++) {
            ushort4 pk;
            pk.x = f2bf(o_[t][f][0] * inv);
            pk.y = f2bf(o_[t][f][1] * inv);
            pk.z = f2bf(o_[t][f][2] * inv);
            pk.w = f2bf(o_[t][f][3] * inv);
            *(ushort4*)&O[((size_t)(b*S + qg))*1024 + h*64 + f*16 + fg*4] = pk;
        }
    }
}

extern "C" void kernel_launch(void* const* d_in, const int* in_sizes, int n_in,
                              void* d_out, int out_size, void* d_ws, size_t ws_size,
                              hipStream_t stream)
{
    const float* x     = (const float*)d_in[0];
    const float* w_in  = (const float*)d_in[1];
    const float* b_in  = (const float*)d_in[2];
    const float* w_out = (const float*)d_in[3];
    const float* b_out = (const float*)d_in[4];
    float* out = (float*)d_out;

    const int B = 2, S = 2048, D = 1024, H = 16;
    const int M = B * S;  // 4096

    if (ws_size < (40u << 20)) return;  // need 40 MB scratch
    char* ws = (char*)d_ws;
    ushort* xb     = (ushort*)(ws);              // 8MB: x bf16, later reused as attn_out
    ushort* w_inT  = (ushort*)(ws + (8u << 20)); // 6MB
    ushort* w_outT = (ushort*)(ws + (14u << 20));// 2MB
    ushort* qb     = (ushort*)(ws + (16u << 20));// 8MB
    ushort* kb     = (ushort*)(ws + (24u << 20));// 8MB
    ushort* vtb    = (ushort*)(ws + (32u << 20));// 8MB

    k_prep<<<6144, 256, 0, stream>>>(x, xb, w_in, w_inT, w_out, w_outT);
    k_gemm<0,4><<<dim3(3*D/128, M/128), 256, 0, stream>>>(xb, w_inT, b_in, qb, kb, vtb, nullptr, M, 3*D, D, S);
    k_attn<<<1024, 128, 0, stream>>>(qb, kb, vtb, xb, S);
    k_gemm<1,2><<<dim3(D/64, M/128), 256, 0, stream>>>(xb, w_outT, b_out, nullptr, nullptr, nullptr, out, M, D, D, S);
}